// Round 7
// baseline (167.570 us; speedup 1.0000x reference)
//
#include <hip/hip_runtime.h>

// Problem constants
#define D_B 8
#define N_T 2048
#define NN  64
#define N_H 8
#define N_C 32   // u-chunks of 64
#define NP  72   // padded LDS row stride (bf16): 144 B rows, 16B-aligned, 2-way alias (free)
#define MAGIC 0x7E57C0DE

typedef __bf16 bf16;
typedef bf16 bf16x8 __attribute__((ext_vector_type(8)));
typedef bf16 bf16x4 __attribute__((ext_vector_type(4)));
typedef float f32x4 __attribute__((ext_vector_type(4)));

static __device__ __forceinline__ f32x4 mfma16(bf16x8 a, bf16x8 b, f32x4 c) {
    // a_frag[j] = A[lane&15][(lane>>4)*8+j]; b_frag[j] = B[(lane>>4)*8+j][lane&15]
    // d[r] = D[(lane>>4)*4+r][lane&15]
    return __builtin_amdgcn_mfma_f32_16x16x32_bf16(a, b, c, 0, 0, 0);
}

static __device__ __forceinline__ bf16x8 ldcvt8(const float* p) {
    const f32x4 v0 = *(const f32x4*)p;
    const f32x4 v1 = *(const f32x4*)(p + 4);
    bf16x8 r;
#pragma unroll
    for (int k = 0; k < 4; k++) { r[k] = (bf16)v0[k]; r[4 + k] = (bf16)v1[k]; }
    return r;
}

// ---------------------------------------------------------------------------
// Fused kernel, 512 blocks (gid: c slowest -> dispatch order matches dep order).
// Phase A (z = head-half): Qrd/Erd/dGq for heads {4z..4z+3} of chunk (b,c);
//   publish flag[b*64 + 2c + z] (agent release). Poison 0xAA != MAGIC, so
//   flags need no init kernel.
// Phase B (z = t-half): spin (wave0) on 2c predecessor flags + sibling flag,
//   acquire + threadfence; inline scan -> Gb; barrier-free head loop with
//   per-wave S slabs; prefix term; h-group reduction; out.
// Deadlock-free: publish strictly precedes any spin; c ascends with gid;
// 512 blocks x 2/CU fully resident.
// ---------------------------------------------------------------------------
__global__ __launch_bounds__(256, 2) void k_all(
    const float* __restrict__ rp, const float* __restrict__ Qm,
    const float* __restrict__ Em,
    bf16* __restrict__ dGq, bf16* __restrict__ Qrd, bf16* __restrict__ Erd,
    int* flags, float* __restrict__ out)
{
    __shared__ bf16 Rl[64 * NP];   // R chunk [u][j] — live through BOTH phases
    __shared__ bf16 Ql[64 * NP];   // A: Q_h [i'][j]      | B: Gb (Gcum [i][i'])
    __shared__ bf16 El[64 * NP];   // A: E_h [i][j]       | B: Sl (4 wave S slabs)
    __shared__ bf16 QT[64 * NP];   // A: Qr^T / dG stage  | B: Ob (32x65 f32)
    __shared__ bf16 ET[64 * NP];   // A: Er^T [i][u]
    __shared__ bf16 QU[64 * NP];   // A: Qr [u][i'] flush layout
    bf16* Gb = Ql;
    bf16* Sl = El;
    float* Ob = (float*)QT;

    const int gid = blockIdx.x;
    const int c = gid >> 4, b = (gid >> 1) & 7, z = gid & 1;
    const int tid = threadIdx.x;
    const int w = tid >> 6, l = tid & 63, q = l >> 4, l16 = l & 15;
    const int row = tid >> 2, col = (tid & 3) * 16;

    // ================= Phase A =================
    {
        const float* src = rp + ((size_t)b * N_T + c * 64 + row) * NN + col;
        *(bf16x8*)&Rl[row * NP + col]     = ldcvt8(src);
        *(bf16x8*)&Rl[row * NP + col + 8] = ldcvt8(src + 8);
    }
    __syncthreads();
    const bf16x8 a0 = *(const bf16x8*)&Rl[(w * 16 + l16) * NP + q * 8];
    const bf16x8 a1 = *(const bf16x8*)&Rl[(w * 16 + l16) * NP + 32 + q * 8];

    f32x4 dacc[4];
#pragma unroll
    for (int ns = 0; ns < 4; ns++) { f32x4 zz = {0.f, 0.f, 0.f, 0.f}; dacc[ns] = zz; }

    for (int hh = 0; hh < 4; hh++) {
        const int h = z * 4 + hh;
        {
            const float* qs = Qm + (size_t)h * 4096 + row * 64 + col;
            const float* es = Em + (size_t)h * 4096 + row * 64 + col;
            *(bf16x8*)&Ql[row * NP + col]     = ldcvt8(qs);
            *(bf16x8*)&Ql[row * NP + col + 8] = ldcvt8(qs + 8);
            *(bf16x8*)&El[row * NP + col]     = ldcvt8(es);
            *(bf16x8*)&El[row * NP + col + 8] = ldcvt8(es + 8);
        }
        __syncthreads();
        const size_t tb = (((size_t)(b * N_C + c)) * N_H + h) * 4096;
#pragma unroll
        for (int ns = 0; ns < 4; ns++) {
            bf16x8 b0 = *(const bf16x8*)&Ql[(ns * 16 + l16) * NP + q * 8];
            bf16x8 b1 = *(const bf16x8*)&Ql[(ns * 16 + l16) * NP + 32 + q * 8];
            f32x4 zz = {0.f, 0.f, 0.f, 0.f};
            f32x4 s = mfma16(a0, b0, zz);
            s = mfma16(a1, b1, s);
            bf16x4 p;
#pragma unroll
            for (int r = 0; r < 4; r++) p[r] = (bf16)s[r];
            *(bf16x4*)&QT[(ns * 16 + l16) * NP + w * 16 + q * 4] = p;   // [i'][u]
#pragma unroll
            for (int r = 0; r < 4; r++)                                  // [u][i']
                QU[(w * 16 + q * 4 + r) * NP + ns * 16 + l16] = p[r];
            b0 = *(const bf16x8*)&El[(ns * 16 + l16) * NP + q * 8];
            b1 = *(const bf16x8*)&El[(ns * 16 + l16) * NP + 32 + q * 8];
            f32x4 s2 = mfma16(a0, b0, zz);
            s2 = mfma16(a1, b1, s2);
#pragma unroll
            for (int r = 0; r < 4; r++) p[r] = (bf16)s2[r];
            *(bf16x4*)&ET[(ns * 16 + l16) * NP + w * 16 + q * 4] = p;   // [i][u]
        }
        __syncthreads();
        {
            const bf16x8 qa0 = *(const bf16x8*)&QT[(w * 16 + l16) * NP + q * 8];
            const bf16x8 qa1 = *(const bf16x8*)&QT[(w * 16 + l16) * NP + 32 + q * 8];
#pragma unroll
            for (int ns = 0; ns < 4; ns++) {
                const bf16x8 e0 = *(const bf16x8*)&ET[(ns * 16 + l16) * NP + q * 8];
                const bf16x8 e1 = *(const bf16x8*)&ET[(ns * 16 + l16) * NP + 32 + q * 8];
                dacc[ns] = mfma16(qa0, e0, dacc[ns]);
                dacc[ns] = mfma16(qa1, e1, dacc[ns]);
            }
        }
        {
            bf16* de = Erd + tb + row * 64 + col;
            *(bf16x8*)de       = *(const bf16x8*)&ET[row * NP + col];
            *(bf16x8*)(de + 8) = *(const bf16x8*)&ET[row * NP + col + 8];
            bf16* dq = Qrd + tb + row * 64 + col;
            *(bf16x8*)dq       = *(const bf16x8*)&QU[row * NP + col];
            *(bf16x8*)(dq + 8) = *(const bf16x8*)&QU[row * NP + col + 8];
        }
        __syncthreads();
    }
    // dG fragments (row i'=w*16+q*4+r, col i=ns*16+l16) -> QT as [i][i'], flush
#pragma unroll
    for (int ns = 0; ns < 4; ns++) {
        bf16x4 p;
#pragma unroll
        for (int r = 0; r < 4; r++) p[r] = (bf16)dacc[ns][r];
        *(bf16x4*)&QT[(ns * 16 + l16) * NP + w * 16 + q * 4] = p;
    }
    __syncthreads();
    {
        bf16* dst = dGq + ((size_t)b * N_C * 2 + c * 2 + z) * 4096 + row * 64 + col;
        *(bf16x8*)dst       = *(const bf16x8*)&QT[row * NP + col];
        *(bf16x8*)(dst + 8) = *(const bf16x8*)&QT[row * NP + col + 8];
    }
    __syncthreads();   // drains vmem (vmcnt0 before barrier) -> stores complete
    if (tid == 0)
        __hip_atomic_store(&flags[b * 64 + c * 2 + z], MAGIC,
                           __ATOMIC_RELEASE, __HIP_MEMORY_SCOPE_AGENT);

    // ================= wait for dependencies =================
    const int nt = 2 * c;   // predecessor tiles; + sibling flag
    if (tid <= nt) {        // tid 0..2c (<=62): all in wave 0
        const int fi = b * 64 + ((tid < nt) ? tid : (c * 2 + (1 - z)));
        while (__hip_atomic_load(&flags[fi], __ATOMIC_ACQUIRE,
                                 __HIP_MEMORY_SCOPE_AGENT) != MAGIC)
            __builtin_amdgcn_s_sleep(2);
    }
    __syncthreads();
    __threadfence();   // agent-scope acquire fence: invalidate stale L1/L2 lines

    // ================= Phase B =================
    // inline exclusive scan over nt tiles -> Gb [i][i']
    {
        float run[16];
#pragma unroll
        for (int k = 0; k < 16; k++) run[k] = 0.f;
        const bf16* base = dGq + (size_t)b * N_C * 2 * 4096 + tid * 16;
        for (int t = 0; t < nt; t++) {
            const bf16x8 v0 = *(const bf16x8*)(base + (size_t)t * 4096);
            const bf16x8 v1 = *(const bf16x8*)(base + (size_t)t * 4096 + 8);
#pragma unroll
            for (int k = 0; k < 8; k++) { run[k] += (float)v0[k]; run[8 + k] += (float)v1[k]; }
        }
        bf16x8 o0, o1;
#pragma unroll
        for (int k = 0; k < 8; k++) { o0[k] = (bf16)run[k]; o1[k] = (bf16)run[8 + k]; }
        *(bf16x8*)&Gb[(tid >> 2) * NP + (tid & 3) * 16] = o0;
        *(bf16x8*)&Gb[(tid >> 2) * NP + (tid & 3) * 16 + 8] = o1;
    }
    __syncthreads();

    // A-frags for t rows from still-resident Rl (t = c*64 + z*32 + s*16 + l16)
    const int s = w & 1, g = w >> 1;
    const bf16x8 ra0 = *(const bf16x8*)&Rl[(z * 32 + s * 16 + l16) * NP + q * 8];
    const bf16x8 ra1 = *(const bf16x8*)&Rl[(z * 32 + s * 16 + l16) * NP + 32 + q * 8];

    bf16* Sw = Sl + w * 16 * NP;
    const int NU = z ? 4 : 2;   // u-tiles needed under the causal mask
    f32x4 acc[4];
#pragma unroll
    for (int ns = 0; ns < 4; ns++) { f32x4 zz = {0.f, 0.f, 0.f, 0.f}; acc[ns] = zz; }

    for (int hh = 0; hh < 4; hh++) {
        const int h = g * 4 + hh;
        const bf16* Qh = Qrd + (((size_t)(b * N_C + c)) * N_H + h) * 4096;  // [u][i']
        const bf16* Eh = Erd + (((size_t)(b * N_C + c)) * N_H + h) * 4096;  // [i][u]
        for (int nu = 0; nu < NU; nu++) {
            const bf16x8 b0 = *(const bf16x8*)&Qh[(nu * 16 + l16) * 64 + q * 8];
            const bf16x8 b1 = *(const bf16x8*)&Qh[(nu * 16 + l16) * 64 + 32 + q * 8];
            f32x4 zz = {0.f, 0.f, 0.f, 0.f};
            f32x4 sv = mfma16(ra0, b0, zz);
            sv = mfma16(ra1, b1, sv);
            const int u_loc = nu * 16 + l16;
#pragma unroll
            for (int r = 0; r < 4; r++) {
                const int t_loc = z * 32 + s * 16 + q * 4 + r;
                Sw[(q * 4 + r) * NP + u_loc] = (u_loc <= t_loc) ? (bf16)sv[r] : (bf16)0.f;
            }
        }
        // same-wave LDS RAW (DS in-order per wave); S back as A-operand
        const bf16x8 sa0 = *(const bf16x8*)&Sw[l16 * NP + q * 8];
#pragma unroll
        for (int ns = 0; ns < 4; ns++) {
            const bf16x8 e0 = *(const bf16x8*)&Eh[(ns * 16 + l16) * 64 + q * 8];
            acc[ns] = mfma16(sa0, e0, acc[ns]);
        }
        if (z) {
            const bf16x8 sa1 = *(const bf16x8*)&Sw[l16 * NP + 32 + q * 8];
#pragma unroll
            for (int ns = 0; ns < 4; ns++) {
                const bf16x8 e1 = *(const bf16x8*)&Eh[(ns * 16 + l16) * 64 + 32 + q * 8];
                acc[ns] = mfma16(sa1, e1, acc[ns]);
            }
        }
    }
    // prefix term (g==1): O += R_t * Gcum, B storage [n=i][k=i'] = Gb
    if (g == 1) {
#pragma unroll
        for (int ns = 0; ns < 4; ns++) {
            const bf16x8 g0 = *(const bf16x8*)&Gb[(ns * 16 + l16) * NP + q * 8];
            const bf16x8 g1 = *(const bf16x8*)&Gb[(ns * 16 + l16) * NP + 32 + q * 8];
            acc[ns] = mfma16(ra0, g0, acc[ns]);
            acc[ns] = mfma16(ra1, g1, acc[ns]);
        }
    }
    __syncthreads();   // S-slab reads done before Ob overwrites QT region? (Ob!=Sl; protects nothing else) keep for phase separation
    if (g == 0) {
#pragma unroll
        for (int ns = 0; ns < 4; ns++)
#pragma unroll
            for (int r = 0; r < 4; r++)
                Ob[(s * 16 + q * 4 + r) * 65 + ns * 16 + l16] = acc[ns][r];
    }
    __syncthreads();
    if (g == 1) {
        const int t0 = c * 64 + z * 32;
#pragma unroll
        for (int ns = 0; ns < 4; ns++)
#pragma unroll
            for (int r = 0; r < 4; r++) {
                const float sum = acc[ns][r] + Ob[(s * 16 + q * 4 + r) * 65 + ns * 16 + l16];
                out[((size_t)b * N_T + t0 + s * 16 + q * 4 + r) * NN + ns * 16 + l16] = sum;
            }
    }
}

// ---------------------------------------------------------------------------
extern "C" void kernel_launch(void* const* d_in, const int* in_sizes, int n_in,
                              void* d_out, int out_size, void* d_ws, size_t ws_size,
                              hipStream_t stream) {
    const float* rp = (const float*)d_in[0];   // (8, 2048, 64) fp32
    const float* Qm = (const float*)d_in[1];   // (8, 64, 64)
    const float* Em = (const float*)d_in[2];   // (8, 64, 64)
    float* out = (float*)d_out;                // (8, 2048, 64) fp32

    // ws: dGq 4.2 MB + Qrd 16.8 MB + Erd 16.8 MB + flags 2 KB (~38 MB)
    bf16* dGq = (bf16*)d_ws;
    bf16* Qrd = dGq + (size_t)D_B * N_C * 2 * 4096;
    bf16* Erd = Qrd + (size_t)D_B * N_C * N_H * 4096;
    int* flags = (int*)(Erd + (size_t)D_B * N_C * N_H * 4096);

    k_all<<<dim3(D_B * N_C * 2), 256, 0, stream>>>(rp, Qm, Em, dGq, Qrd, Erd,
                                                   flags, out);
}

// Round 8
// 129.253 us; speedup vs baseline: 1.2965x; 1.2965x over previous
//
#include <hip/hip_runtime.h>

// Problem constants
#define D_B 8
#define N_T 2048
#define NN  64
#define N_H 8
#define N_C 32   // u-chunks of 64
#define NP  72   // padded LDS row stride (bf16): 144 B rows, 16B-aligned, 2-way alias (free)

typedef __bf16 bf16;
typedef bf16 bf16x8 __attribute__((ext_vector_type(8)));
typedef bf16 bf16x4 __attribute__((ext_vector_type(4)));
typedef float f32x4 __attribute__((ext_vector_type(4)));

static __device__ __forceinline__ f32x4 mfma16(bf16x8 a, bf16x8 b, f32x4 c) {
    // a_frag[j] = A[lane&15][(lane>>4)*8+j]; b_frag[j] = B[(lane>>4)*8+j][lane&15]
    // d[r] = D[(lane>>4)*4+r][lane&15]
    return __builtin_amdgcn_mfma_f32_16x16x32_bf16(a, b, c, 0, 0, 0);
}

static __device__ __forceinline__ bf16x8 ldcvt8(const float* p) {
    const f32x4 v0 = *(const f32x4*)p;
    const f32x4 v1 = *(const f32x4*)(p + 4);
    bf16x8 r;
#pragma unroll
    for (int k = 0; k < 4; k++) { r[k] = (bf16)v0[k]; r[4 + k] = (bf16)v1[k]; }
    return r;
}

// ---------------------------------------------------------------------------
// K1: block (b, c, qt) handles heads {2qt, 2qt+1} of chunk c (R5 structure):
//   Qrd[b,c,h][u][i'] (direct store), Erd[b,c,h][i][u] (LDS-transposed flush),
//   dGq[b,c,qt][i][i'] (pre-transposed bf16), Rbf (qt==0).
// R A-frags read DIRECTLY from global fp32 (no Rl buffer): 4 LDS buffers
// = 36.9 KB -> 4 blocks/CU. Grid (D_B, N_C, 4): linear%8 = b (XCD-local).
// ---------------------------------------------------------------------------
__global__ __launch_bounds__(256, 4) void k_dg(
    const float* __restrict__ rp, const float* __restrict__ Qm,
    const float* __restrict__ Em,
    bf16* __restrict__ dGq, bf16* __restrict__ Rbf,
    bf16* __restrict__ Qrd, bf16* __restrict__ Erd)
{
    __shared__ bf16 Ql[64 * NP];   // Q_h [i'][j]
    __shared__ bf16 El[64 * NP];   // E_h [i][j]
    __shared__ bf16 QT[64 * NP];   // Qr tile [i'][u]; dG [i][i'] staging at tail
    __shared__ bf16 ET[64 * NP];   // Er tile [i][u]
    const int b = blockIdx.x, c = blockIdx.y, qt = blockIdx.z;
    const int tid = threadIdx.x;
    const int w = tid >> 6, l = tid & 63, q = l >> 4, l16 = l & 15;
    const int row = tid >> 2, col = (tid & 3) * 16;

    // R A-frags straight from global fp32 (rows u = c*64 + w*16 + l16)
    const float* rrow = rp + ((size_t)b * N_T + c * 64 + w * 16 + l16) * NN;
    const bf16x8 a0 = ldcvt8(rrow + q * 8);
    const bf16x8 a1 = ldcvt8(rrow + 32 + q * 8);

    // Rbf emit (qt==0 only), independent of the compute path
    if (qt == 0) {
        const float* src = rp + ((size_t)b * N_T + c * 64 + row) * NN + col;
        bf16* d = Rbf + ((size_t)b * N_T + c * 64 + row) * NN + col;
        *(bf16x8*)d       = ldcvt8(src);
        *(bf16x8*)(d + 8) = ldcvt8(src + 8);
    }

    f32x4 dacc[4];
#pragma unroll
    for (int ns = 0; ns < 4; ns++) { f32x4 z = {0.f, 0.f, 0.f, 0.f}; dacc[ns] = z; }

    for (int hh = 0; hh < 2; hh++) {
        const int h = qt * 2 + hh;
        // stage Q_h/E_h fp32 -> bf16 LDS (coalesced; L2-resident broadcast)
        {
            const float* qs = Qm + (size_t)h * 4096 + row * 64 + col;
            const float* es = Em + (size_t)h * 4096 + row * 64 + col;
            *(bf16x8*)&Ql[row * NP + col]     = ldcvt8(qs);
            *(bf16x8*)&Ql[row * NP + col + 8] = ldcvt8(qs + 8);
            *(bf16x8*)&El[row * NP + col]     = ldcvt8(es);
            *(bf16x8*)&El[row * NP + col + 8] = ldcvt8(es + 8);
        }
        __syncthreads();
        const size_t tb = (((size_t)(b * N_C + c)) * N_H + h) * 4096;
#pragma unroll
        for (int ns = 0; ns < 4; ns++) {
            // Qr[u,i'] : B storage [n=i'][k=j] = Ql
            bf16x8 b0 = *(const bf16x8*)&Ql[(ns * 16 + l16) * NP + q * 8];
            bf16x8 b1 = *(const bf16x8*)&Ql[(ns * 16 + l16) * NP + 32 + q * 8];
            f32x4 z = {0.f, 0.f, 0.f, 0.f};
            f32x4 s = mfma16(a0, b0, z);
            s = mfma16(a1, b1, s);
            bf16x4 p;
#pragma unroll
            for (int r = 0; r < 4; r++) p[r] = (bf16)s[r];
            // Qrd direct store (row=u, col=i'): 32-B segments (R5-proven)
#pragma unroll
            for (int r = 0; r < 4; r++)
                Qrd[tb + (w * 16 + q * 4 + r) * 64 + ns * 16 + l16] = p[r];
            *(bf16x4*)&QT[(ns * 16 + l16) * NP + w * 16 + q * 4] = p;  // [i'][u]
            // Er[u,i]
            b0 = *(const bf16x8*)&El[(ns * 16 + l16) * NP + q * 8];
            b1 = *(const bf16x8*)&El[(ns * 16 + l16) * NP + 32 + q * 8];
            f32x4 s2 = mfma16(a0, b0, z);
            s2 = mfma16(a1, b1, s2);
#pragma unroll
            for (int r = 0; r < 4; r++) p[r] = (bf16)s2[r];
            *(bf16x4*)&ET[(ns * 16 + l16) * NP + w * 16 + q * 4] = p;  // [i][u]
        }
        __syncthreads();
        // dG[i'][i] += Qr^T Er : A from QT [i'][u], B from ET [i][u]
        {
            const bf16x8 qa0 = *(const bf16x8*)&QT[(w * 16 + l16) * NP + q * 8];
            const bf16x8 qa1 = *(const bf16x8*)&QT[(w * 16 + l16) * NP + 32 + q * 8];
#pragma unroll
            for (int ns = 0; ns < 4; ns++) {
                const bf16x8 e0 = *(const bf16x8*)&ET[(ns * 16 + l16) * NP + q * 8];
                const bf16x8 e1 = *(const bf16x8*)&ET[(ns * 16 + l16) * NP + 32 + q * 8];
                dacc[ns] = mfma16(qa0, e0, dacc[ns]);
                dacc[ns] = mfma16(qa1, e1, dacc[ns]);
            }
        }
        // Erd coalesced flush from ET (8 KB contiguous)
        {
            const bf16x8 v0 = *(const bf16x8*)&ET[row * NP + col];
            const bf16x8 v1 = *(const bf16x8*)&ET[row * NP + col + 8];
            bf16* d = Erd + tb + row * 64 + col;
            *(bf16x8*)d = v0;
            *(bf16x8*)(d + 8) = v1;
        }
        __syncthreads();   // QT/ET/Ql/El reads done before next head overwrites
    }
    // transpose dacc (D row=i', col=i) -> QT as [i][i'], coalesced store
#pragma unroll
    for (int ns = 0; ns < 4; ns++) {
        bf16x4 p;
#pragma unroll
        for (int r = 0; r < 4; r++) p[r] = (bf16)dacc[ns][r];
        *(bf16x4*)&QT[(ns * 16 + l16) * NP + w * 16 + q * 4] = p;
    }
    __syncthreads();
    {
        bf16* dst = dGq + (((size_t)(b * N_C + c)) * 4 + qt) * 4096 + row * 64 + col;
        *(bf16x8*)dst       = *(const bf16x8*)&QT[row * NP + col];
        *(bf16x8*)(dst + 8) = *(const bf16x8*)&QT[row * NP + col + 8];
    }
}

// ---------------------------------------------------------------------------
// K2: block (b, c, half) computes out rows [c*64 + half*32, +32):
//   inline scan of the 4c quarter tiles -> Gb; barrier-free head loop with
//   per-wave private S slabs; half=0 skips masked-out upper u-range.
// Grid (D_B, N_C, 2): linear%8 = b; 512 blocks.
// ---------------------------------------------------------------------------
__global__ __launch_bounds__(256, 4) void k_out(
    const bf16* __restrict__ dGq, const bf16* __restrict__ Rbf,
    const bf16* __restrict__ Qrd, const bf16* __restrict__ Erd,
    float* __restrict__ out)
{
    __shared__ bf16 Gb[64 * NP];      // Gcum [i][i']
    __shared__ bf16 Sl[4 * 16 * NP];  // per-wave S slabs
    __shared__ float Ob[32 * 65];     // h-group reduction
    const int b = blockIdx.x, c = blockIdx.y, half = blockIdx.z;
    const int tid = threadIdx.x;
    const int w = tid >> 6, l = tid & 63, q = l >> 4, l16 = l & 15;
    const int s = w & 1, g = w >> 1;

    // ---- inline exclusive scan over quarter tiles (4c x 16 B per thread)
    {
        float run[16];
#pragma unroll
        for (int k = 0; k < 16; k++) run[k] = 0.f;
        const bf16* base = dGq + (size_t)b * N_C * 4 * 4096 + tid * 16;
        const int nt = 4 * c;
        for (int t = 0; t < nt; t++) {
            const bf16x8 v0 = *(const bf16x8*)(base + (size_t)t * 4096);
            const bf16x8 v1 = *(const bf16x8*)(base + (size_t)t * 4096 + 8);
#pragma unroll
            for (int k = 0; k < 8; k++) { run[k] += (float)v0[k]; run[8 + k] += (float)v1[k]; }
        }
        // elem idx = tid*16+k -> i = tid>>2, i' = (tid&3)*16 + k
        bf16x8 o0, o1;
#pragma unroll
        for (int k = 0; k < 8; k++) { o0[k] = (bf16)run[k]; o1[k] = (bf16)run[8 + k]; }
        *(bf16x8*)&Gb[(tid >> 2) * NP + (tid & 3) * 16] = o0;
        *(bf16x8*)&Gb[(tid >> 2) * NP + (tid & 3) * 16 + 8] = o1;
    }
    __syncthreads();

    // A-frags: R rows t = c*64 + half*32 + s*16 + l16
    const int trow = c * 64 + half * 32 + s * 16 + l16;
    const bf16x8 ra0 = *(const bf16x8*)&Rbf[((size_t)b * N_T + trow) * NN + q * 8];
    const bf16x8 ra1 = *(const bf16x8*)&Rbf[((size_t)b * N_T + trow) * NN + 32 + q * 8];

    bf16* Sw = Sl + w * 16 * NP;
    const int NU = half ? 4 : 2;   // u-tiles needed under the causal mask
    f32x4 acc[4];
#pragma unroll
    for (int ns = 0; ns < 4; ns++) { f32x4 z = {0.f, 0.f, 0.f, 0.f}; acc[ns] = z; }

    for (int hh = 0; hh < 4; hh++) {
        const int h = g * 4 + hh;
        const bf16* Qh = Qrd + (((size_t)(b * N_C + c)) * N_H + h) * 4096;  // [u][i']
        const bf16* Eh = Erd + (((size_t)(b * N_C + c)) * N_H + h) * 4096;  // [i][u]
        // S[t][u] = sum_i' R[t,i'] Qr[u,i'], masked -> per-wave slab
        for (int nu = 0; nu < NU; nu++) {
            const bf16x8 b0 = *(const bf16x8*)&Qh[(nu * 16 + l16) * 64 + q * 8];
            const bf16x8 b1 = *(const bf16x8*)&Qh[(nu * 16 + l16) * 64 + 32 + q * 8];
            f32x4 z = {0.f, 0.f, 0.f, 0.f};
            f32x4 sv = mfma16(ra0, b0, z);
            sv = mfma16(ra1, b1, sv);
            const int u_loc = nu * 16 + l16;
#pragma unroll
            for (int r = 0; r < 4; r++) {
                const int t_loc = half * 32 + s * 16 + q * 4 + r;
                Sw[(q * 4 + r) * NP + u_loc] = (u_loc <= t_loc) ? (bf16)sv[r] : (bf16)0.f;
            }
        }
        // same-wave LDS RAW (DS in-order per wave); S back as A-operand
        const bf16x8 sa0 = *(const bf16x8*)&Sw[l16 * NP + q * 8];
#pragma unroll
        for (int ns = 0; ns < 4; ns++) {
            const bf16x8 e0 = *(const bf16x8*)&Eh[(ns * 16 + l16) * 64 + q * 8];
            acc[ns] = mfma16(sa0, e0, acc[ns]);
        }
        if (half) {
            const bf16x8 sa1 = *(const bf16x8*)&Sw[l16 * NP + 32 + q * 8];
#pragma unroll
            for (int ns = 0; ns < 4; ns++) {
                const bf16x8 e1 = *(const bf16x8*)&Eh[(ns * 16 + l16) * 64 + 32 + q * 8];
                acc[ns] = mfma16(sa1, e1, acc[ns]);
            }
        }
    }
    // prefix term (g==1): O += R_t * Gcum, B storage [n=i][k=i'] = Gb
    if (g == 1) {
#pragma unroll
        for (int ns = 0; ns < 4; ns++) {
            const bf16x8 g0 = *(const bf16x8*)&Gb[(ns * 16 + l16) * NP + q * 8];
            const bf16x8 g1 = *(const bf16x8*)&Gb[(ns * 16 + l16) * NP + 32 + q * 8];
            acc[ns] = mfma16(ra0, g0, acc[ns]);
            acc[ns] = mfma16(ra1, g1, acc[ns]);
        }
    }
    if (g == 0) {
#pragma unroll
        for (int ns = 0; ns < 4; ns++)
#pragma unroll
            for (int r = 0; r < 4; r++)
                Ob[(s * 16 + q * 4 + r) * 65 + ns * 16 + l16] = acc[ns][r];
    }
    __syncthreads();
    if (g == 1) {
        const int t0 = c * 64 + half * 32;
#pragma unroll
        for (int ns = 0; ns < 4; ns++)
#pragma unroll
            for (int r = 0; r < 4; r++) {
                const float sum = acc[ns][r] + Ob[(s * 16 + q * 4 + r) * 65 + ns * 16 + l16];
                out[((size_t)b * N_T + t0 + s * 16 + q * 4 + r) * NN + ns * 16 + l16] = sum;
            }
    }
}

// ---------------------------------------------------------------------------
extern "C" void kernel_launch(void* const* d_in, const int* in_sizes, int n_in,
                              void* d_out, int out_size, void* d_ws, size_t ws_size,
                              hipStream_t stream) {
    const float* rp = (const float*)d_in[0];   // (8, 2048, 64) fp32
    const float* Qm = (const float*)d_in[1];   // (8, 64, 64)
    const float* Em = (const float*)d_in[2];   // (8, 64, 64)
    float* out = (float*)d_out;                // (8, 2048, 64) fp32

    // ws: dGq 8.4 MB + Rbf 2 MB + Qrd 16.8 MB + Erd 16.8 MB  (~44 MB)
    bf16* dGq = (bf16*)d_ws;
    bf16* Rbf = dGq + (size_t)D_B * N_C * 4 * 4096;
    bf16* Qrd = Rbf + (size_t)D_B * N_T * NN;
    bf16* Erd = Qrd + (size_t)D_B * N_C * N_H * 4096;

    k_dg<<<dim3(D_B, N_C, 4), 256, 0, stream>>>(rp, Qm, Em, dGq, Rbf, Qrd, Erd);
    k_out<<<dim3(D_B, N_C, 2), 256, 0, stream>>>(dGq, Rbf, Qrd, Erd, out);
}

// Round 9
// 103.343 us; speedup vs baseline: 1.6215x; 1.2507x over previous
//
#include <hip/hip_runtime.h>

// Problem constants
#define D_B 8
#define N_T 2048
#define NN  64
#define N_H 8
#define N_C 32   // u-chunks of 64
#define NP  72   // padded LDS row stride (bf16): 144 B rows, 16B-aligned, 2-way alias (free)

typedef __bf16 bf16;
typedef bf16 bf16x8 __attribute__((ext_vector_type(8)));
typedef bf16 bf16x4 __attribute__((ext_vector_type(4)));
typedef float f32x4 __attribute__((ext_vector_type(4)));

static __device__ __forceinline__ f32x4 mfma16(bf16x8 a, bf16x8 b, f32x4 c) {
    // a_frag[j] = A[lane&15][(lane>>4)*8+j]; b_frag[j] = B[(lane>>4)*8+j][lane&15]
    // d[r] = D[(lane>>4)*4+r][lane&15]
    return __builtin_amdgcn_mfma_f32_16x16x32_bf16(a, b, c, 0, 0, 0);
}

static __device__ __forceinline__ bf16x8 ldcvt8(const float* p) {
    const f32x4 v0 = *(const f32x4*)p;
    const f32x4 v1 = *(const f32x4*)(p + 4);
    bf16x8 r;
#pragma unroll
    for (int k = 0; k < 4; k++) { r[k] = (bf16)v0[k]; r[4 + k] = (bf16)v1[k]; }
    return r;
}

// ---------------------------------------------------------------------------
// K1 (R8-proven, ~4-5 us): block (b, c, qt) handles heads {2qt, 2qt+1}:
//   Qrd[b,c,h][u][i'] (direct store), Erd[b,c,h][i][u] (LDS-transposed flush),
//   dGq[b,c,qt][i][i'] (pre-transposed bf16), Rbf (qt==0).
// R A-frags direct from global fp32. 36.9 KB LDS -> 4 blocks/CU.
// Grid (D_B, N_C, 4): linear%8 = b (XCD-local).
// ---------------------------------------------------------------------------
__global__ __launch_bounds__(256, 4) void k_dg(
    const float* __restrict__ rp, const float* __restrict__ Qm,
    const float* __restrict__ Em,
    bf16* __restrict__ dGq, bf16* __restrict__ Rbf,
    bf16* __restrict__ Qrd, bf16* __restrict__ Erd)
{
    __shared__ bf16 Ql[64 * NP];   // Q_h [i'][j]
    __shared__ bf16 El[64 * NP];   // E_h [i][j]
    __shared__ bf16 QT[64 * NP];   // Qr tile [i'][u]; dG [i][i'] staging at tail
    __shared__ bf16 ET[64 * NP];   // Er tile [i][u]
    const int b = blockIdx.x, c = blockIdx.y, qt = blockIdx.z;
    const int tid = threadIdx.x;
    const int w = tid >> 6, l = tid & 63, q = l >> 4, l16 = l & 15;
    const int row = tid >> 2, col = (tid & 3) * 16;

    // R A-frags straight from global fp32 (rows u = c*64 + w*16 + l16)
    const float* rrow = rp + ((size_t)b * N_T + c * 64 + w * 16 + l16) * NN;
    const bf16x8 a0 = ldcvt8(rrow + q * 8);
    const bf16x8 a1 = ldcvt8(rrow + 32 + q * 8);

    if (qt == 0) {
        const float* src = rp + ((size_t)b * N_T + c * 64 + row) * NN + col;
        bf16* d = Rbf + ((size_t)b * N_T + c * 64 + row) * NN + col;
        *(bf16x8*)d       = ldcvt8(src);
        *(bf16x8*)(d + 8) = ldcvt8(src + 8);
    }

    f32x4 dacc[4];
#pragma unroll
    for (int ns = 0; ns < 4; ns++) { f32x4 z = {0.f, 0.f, 0.f, 0.f}; dacc[ns] = z; }

    for (int hh = 0; hh < 2; hh++) {
        const int h = qt * 2 + hh;
        {
            const float* qs = Qm + (size_t)h * 4096 + row * 64 + col;
            const float* es = Em + (size_t)h * 4096 + row * 64 + col;
            *(bf16x8*)&Ql[row * NP + col]     = ldcvt8(qs);
            *(bf16x8*)&Ql[row * NP + col + 8] = ldcvt8(qs + 8);
            *(bf16x8*)&El[row * NP + col]     = ldcvt8(es);
            *(bf16x8*)&El[row * NP + col + 8] = ldcvt8(es + 8);
        }
        __syncthreads();
        const size_t tb = (((size_t)(b * N_C + c)) * N_H + h) * 4096;
#pragma unroll
        for (int ns = 0; ns < 4; ns++) {
            bf16x8 b0 = *(const bf16x8*)&Ql[(ns * 16 + l16) * NP + q * 8];
            bf16x8 b1 = *(const bf16x8*)&Ql[(ns * 16 + l16) * NP + 32 + q * 8];
            f32x4 z = {0.f, 0.f, 0.f, 0.f};
            f32x4 s = mfma16(a0, b0, z);
            s = mfma16(a1, b1, s);
            bf16x4 p;
#pragma unroll
            for (int r = 0; r < 4; r++) p[r] = (bf16)s[r];
#pragma unroll
            for (int r = 0; r < 4; r++)
                Qrd[tb + (w * 16 + q * 4 + r) * 64 + ns * 16 + l16] = p[r];
            *(bf16x4*)&QT[(ns * 16 + l16) * NP + w * 16 + q * 4] = p;  // [i'][u]
            b0 = *(const bf16x8*)&El[(ns * 16 + l16) * NP + q * 8];
            b1 = *(const bf16x8*)&El[(ns * 16 + l16) * NP + 32 + q * 8];
            f32x4 s2 = mfma16(a0, b0, z);
            s2 = mfma16(a1, b1, s2);
#pragma unroll
            for (int r = 0; r < 4; r++) p[r] = (bf16)s2[r];
            *(bf16x4*)&ET[(ns * 16 + l16) * NP + w * 16 + q * 4] = p;  // [i][u]
        }
        __syncthreads();
        {
            const bf16x8 qa0 = *(const bf16x8*)&QT[(w * 16 + l16) * NP + q * 8];
            const bf16x8 qa1 = *(const bf16x8*)&QT[(w * 16 + l16) * NP + 32 + q * 8];
#pragma unroll
            for (int ns = 0; ns < 4; ns++) {
                const bf16x8 e0 = *(const bf16x8*)&ET[(ns * 16 + l16) * NP + q * 8];
                const bf16x8 e1 = *(const bf16x8*)&ET[(ns * 16 + l16) * NP + 32 + q * 8];
                dacc[ns] = mfma16(qa0, e0, dacc[ns]);
                dacc[ns] = mfma16(qa1, e1, dacc[ns]);
            }
        }
        {
            const bf16x8 v0 = *(const bf16x8*)&ET[row * NP + col];
            const bf16x8 v1 = *(const bf16x8*)&ET[row * NP + col + 8];
            bf16* d = Erd + tb + row * 64 + col;
            *(bf16x8*)d = v0;
            *(bf16x8*)(d + 8) = v1;
        }
        __syncthreads();
    }
#pragma unroll
    for (int ns = 0; ns < 4; ns++) {
        bf16x4 p;
#pragma unroll
        for (int r = 0; r < 4; r++) p[r] = (bf16)dacc[ns][r];
        *(bf16x4*)&QT[(ns * 16 + l16) * NP + w * 16 + q * 4] = p;
    }
    __syncthreads();
    {
        bf16* dst = dGq + (((size_t)(b * N_C + c)) * 4 + qt) * 4096 + row * 64 + col;
        *(bf16x8*)dst       = *(const bf16x8*)&QT[row * NP + col];
        *(bf16x8*)(dst + 8) = *(const bf16x8*)&QT[row * NP + col + 8];
    }
}

// ---------------------------------------------------------------------------
// K2: fold the 4 head-quarters: dG8[b,c] = sum_qt dGq[b,c,qt].
// 4 independent 16 B loads/thread; grid (D_B, N_C): linear%8 = b.
// ---------------------------------------------------------------------------
__global__ __launch_bounds__(256, 4) void k_fold(const bf16* __restrict__ dGq,
                                                 bf16* __restrict__ dG8)
{
    const int b = blockIdx.x, c = blockIdx.y;
    const size_t base = ((size_t)(b * N_C + c)) * 4 * 4096 + threadIdx.x * 16;
    float s[16];
#pragma unroll
    for (int k = 0; k < 16; k++) s[k] = 0.f;
#pragma unroll
    for (int qt = 0; qt < 4; qt++) {
        const bf16x8 v0 = *(const bf16x8*)(dGq + base + (size_t)qt * 4096);
        const bf16x8 v1 = *(const bf16x8*)(dGq + base + (size_t)qt * 4096 + 8);
#pragma unroll
        for (int k = 0; k < 8; k++) { s[k] += (float)v0[k]; s[8 + k] += (float)v1[k]; }
    }
    bf16x8 o0, o1;
#pragma unroll
    for (int k = 0; k < 8; k++) { o0[k] = (bf16)s[k]; o1[k] = (bf16)s[8 + k]; }
    bf16* dst = dG8 + (size_t)(b * N_C + c) * 4096 + threadIdx.x * 16;
    *(bf16x8*)dst = o0;
    *(bf16x8*)(dst + 8) = o1;
}

// ---------------------------------------------------------------------------
// K3: block (b, c, half) computes out rows [c*64 + half*32, +32).
// Scan of <=31 FOLDED tiles, batch-4 prefetched, accumulated in REGISTERS;
// Gb write + single barrier DEFERRED until after the head loop so scan load
// latency overlaps the MFMA stream. half=0 skips masked-out upper u-range.
// Grid (D_B, N_C, 2): linear%8 = b.
// ---------------------------------------------------------------------------
__global__ __launch_bounds__(256, 4) void k_out(
    const bf16* __restrict__ dG8, const bf16* __restrict__ Rbf,
    const bf16* __restrict__ Qrd, const bf16* __restrict__ Erd,
    float* __restrict__ out)
{
    __shared__ bf16 Gb[64 * NP];      // Gcum [i][i'] (written AFTER head loop)
    __shared__ bf16 Sl[4 * 16 * NP];  // per-wave S slabs
    __shared__ float Ob[32 * 65];     // h-group reduction
    const int b = blockIdx.x, c = blockIdx.y, half = blockIdx.z;
    const int tid = threadIdx.x;
    const int w = tid >> 6, l = tid & 63, q = l >> 4, l16 = l & 15;
    const int s = w & 1, g = w >> 1;

    // A-frags: R rows t = c*64 + half*32 + s*16 + l16
    const int trow = c * 64 + half * 32 + s * 16 + l16;
    const bf16x8 ra0 = *(const bf16x8*)&Rbf[((size_t)b * N_T + trow) * NN + q * 8];
    const bf16x8 ra1 = *(const bf16x8*)&Rbf[((size_t)b * N_T + trow) * NN + 32 + q * 8];

    // ---- scan (registers only; no LDS, no barrier yet), batch-4 prefetch
    float run[16];
#pragma unroll
    for (int k = 0; k < 16; k++) run[k] = 0.f;
    {
        const bf16* base = dG8 + (size_t)b * N_C * 4096 + tid * 16;
        int t = 0;
        for (; t + 4 <= c; t += 4) {
            bf16x8 v[4][2];
#pragma unroll
            for (int j = 0; j < 4; j++) {
                v[j][0] = *(const bf16x8*)(base + (size_t)(t + j) * 4096);
                v[j][1] = *(const bf16x8*)(base + (size_t)(t + j) * 4096 + 8);
            }
#pragma unroll
            for (int j = 0; j < 4; j++)
#pragma unroll
                for (int k = 0; k < 8; k++) {
                    run[k] += (float)v[j][0][k];
                    run[8 + k] += (float)v[j][1][k];
                }
        }
        for (; t < c; t++) {
            const bf16x8 v0 = *(const bf16x8*)(base + (size_t)t * 4096);
            const bf16x8 v1 = *(const bf16x8*)(base + (size_t)t * 4096 + 8);
#pragma unroll
            for (int k = 0; k < 8; k++) { run[k] += (float)v0[k]; run[8 + k] += (float)v1[k]; }
        }
    }

    // ---- head loop (barrier-free; per-wave private S slabs)
    bf16* Sw = Sl + w * 16 * NP;
    const int NU = half ? 4 : 2;   // u-tiles needed under the causal mask
    f32x4 acc[4];
#pragma unroll
    for (int ns = 0; ns < 4; ns++) { f32x4 z = {0.f, 0.f, 0.f, 0.f}; acc[ns] = z; }

    for (int hh = 0; hh < 4; hh++) {
        const int h = g * 4 + hh;
        const bf16* Qh = Qrd + (((size_t)(b * N_C + c)) * N_H + h) * 4096;  // [u][i']
        const bf16* Eh = Erd + (((size_t)(b * N_C + c)) * N_H + h) * 4096;  // [i][u]
        for (int nu = 0; nu < NU; nu++) {
            const bf16x8 b0 = *(const bf16x8*)&Qh[(nu * 16 + l16) * 64 + q * 8];
            const bf16x8 b1 = *(const bf16x8*)&Qh[(nu * 16 + l16) * 64 + 32 + q * 8];
            f32x4 z = {0.f, 0.f, 0.f, 0.f};
            f32x4 sv = mfma16(ra0, b0, z);
            sv = mfma16(ra1, b1, sv);
            const int u_loc = nu * 16 + l16;
#pragma unroll
            for (int r = 0; r < 4; r++) {
                const int t_loc = half * 32 + s * 16 + q * 4 + r;
                Sw[(q * 4 + r) * NP + u_loc] = (u_loc <= t_loc) ? (bf16)sv[r] : (bf16)0.f;
            }
        }
        // same-wave LDS RAW (DS in-order per wave); S back as A-operand
        const bf16x8 sa0 = *(const bf16x8*)&Sw[l16 * NP + q * 8];
#pragma unroll
        for (int ns = 0; ns < 4; ns++) {
            const bf16x8 e0 = *(const bf16x8*)&Eh[(ns * 16 + l16) * 64 + q * 8];
            acc[ns] = mfma16(sa0, e0, acc[ns]);
        }
        if (half) {
            const bf16x8 sa1 = *(const bf16x8*)&Sw[l16 * NP + 32 + q * 8];
#pragma unroll
            for (int ns = 0; ns < 4; ns++) {
                const bf16x8 e1 = *(const bf16x8*)&Eh[(ns * 16 + l16) * 64 + 32 + q * 8];
                acc[ns] = mfma16(sa1, e1, acc[ns]);
            }
        }
    }

    // ---- publish Gb (from scan regs) + Ob (g==0 partials); ONE barrier
    {
        // elem idx = tid*16+k -> i = tid>>2, i' = (tid&3)*16 + k
        bf16x8 o0, o1;
#pragma unroll
        for (int k = 0; k < 8; k++) { o0[k] = (bf16)run[k]; o1[k] = (bf16)run[8 + k]; }
        *(bf16x8*)&Gb[(tid >> 2) * NP + (tid & 3) * 16] = o0;
        *(bf16x8*)&Gb[(tid >> 2) * NP + (tid & 3) * 16 + 8] = o1;
    }
    if (g == 0) {
#pragma unroll
        for (int ns = 0; ns < 4; ns++)
#pragma unroll
            for (int r = 0; r < 4; r++)
                Ob[(s * 16 + q * 4 + r) * 65 + ns * 16 + l16] = acc[ns][r];
    }
    __syncthreads();
    if (g == 1) {
        // prefix term: O += R_t * Gcum, B storage [n=i][k=i'] = Gb
#pragma unroll
        for (int ns = 0; ns < 4; ns++) {
            const bf16x8 g0 = *(const bf16x8*)&Gb[(ns * 16 + l16) * NP + q * 8];
            const bf16x8 g1 = *(const bf16x8*)&Gb[(ns * 16 + l16) * NP + 32 + q * 8];
            acc[ns] = mfma16(ra0, g0, acc[ns]);
            acc[ns] = mfma16(ra1, g1, acc[ns]);
        }
        const int t0 = c * 64 + half * 32;
#pragma unroll
        for (int ns = 0; ns < 4; ns++)
#pragma unroll
            for (int r = 0; r < 4; r++) {
                const float sum = acc[ns][r] + Ob[(s * 16 + q * 4 + r) * 65 + ns * 16 + l16];
                out[((size_t)b * N_T + t0 + s * 16 + q * 4 + r) * NN + ns * 16 + l16] = sum;
            }
    }
}

// ---------------------------------------------------------------------------
extern "C" void kernel_launch(void* const* d_in, const int* in_sizes, int n_in,
                              void* d_out, int out_size, void* d_ws, size_t ws_size,
                              hipStream_t stream) {
    const float* rp = (const float*)d_in[0];   // (8, 2048, 64) fp32
    const float* Qm = (const float*)d_in[1];   // (8, 64, 64)
    const float* Em = (const float*)d_in[2];   // (8, 64, 64)
    float* out = (float*)d_out;                // (8, 2048, 64) fp32

    // ws: dGq 8.4 MB + Rbf 2 MB + Qrd 16.8 MB + Erd 16.8 MB + dG8 2.1 MB
    bf16* dGq = (bf16*)d_ws;
    bf16* Rbf = dGq + (size_t)D_B * N_C * 4 * 4096;
    bf16* Qrd = Rbf + (size_t)D_B * N_T * NN;
    bf16* Erd = Qrd + (size_t)D_B * N_C * N_H * 4096;
    bf16* dG8 = Erd + (size_t)D_B * N_C * N_H * 4096;

    k_dg<<<dim3(D_B, N_C, 4), 256, 0, stream>>>(rp, Qm, Em, dGq, Rbf, Qrd, Erd);
    k_fold<<<dim3(D_B, N_C), 256, 0, stream>>>(dGq, dG8);
    k_out<<<dim3(D_B, N_C, 2), 256, 0, stream>>>(dG8, Rbf, Qrd, Erd, out);
}

// Round 10
// 102.760 us; speedup vs baseline: 1.6307x; 1.0057x over previous
//
#include <hip/hip_runtime.h>

// Problem constants
#define D_B 8
#define N_T 2048
#define NN  64
#define N_H 8
#define N_C 32   // u-chunks of 64
#define NP  72   // padded LDS row stride (bf16): 144 B rows, 16B-aligned, 2-way alias (free)

typedef __bf16 bf16;
typedef bf16 bf16x8 __attribute__((ext_vector_type(8)));
typedef bf16 bf16x4 __attribute__((ext_vector_type(4)));
typedef float f32x4 __attribute__((ext_vector_type(4)));

static __device__ __forceinline__ f32x4 mfma16(bf16x8 a, bf16x8 b, f32x4 c) {
    // a_frag[j] = A[lane&15][(lane>>4)*8+j]; b_frag[j] = B[(lane>>4)*8+j][lane&15]
    // d[r] = D[(lane>>4)*4+r][lane&15]
    return __builtin_amdgcn_mfma_f32_16x16x32_bf16(a, b, c, 0, 0, 0);
}

static __device__ __forceinline__ bf16x8 ldcvt8(const float* p) {
    const f32x4 v0 = *(const f32x4*)p;
    const f32x4 v1 = *(const f32x4*)(p + 4);
    bf16x8 r;
#pragma unroll
    for (int k = 0; k < 4; k++) { r[k] = (bf16)v0[k]; r[4 + k] = (bf16)v1[k]; }
    return r;
}

// ---------------------------------------------------------------------------
// K1 (R8/R9-proven): block (b, c, qt) handles heads {2qt, 2qt+1}:
//   Qrd[b,c,h][u][i'] (direct store), Erd[b,c,h][i][u] (LDS-transposed flush),
//   dGq[b,c,qt][i][i'] (pre-transposed bf16), Rbf (qt==0).
// R A-frags direct from global fp32. 36.9 KB LDS -> 4 blocks/CU.
// Grid (D_B, N_C, 4): linear%8 = b (XCD-local).
// ---------------------------------------------------------------------------
__global__ __launch_bounds__(256, 4) void k_dg(
    const float* __restrict__ rp, const float* __restrict__ Qm,
    const float* __restrict__ Em,
    bf16* __restrict__ dGq, bf16* __restrict__ Rbf,
    bf16* __restrict__ Qrd, bf16* __restrict__ Erd)
{
    __shared__ bf16 Ql[64 * NP];   // Q_h [i'][j]
    __shared__ bf16 El[64 * NP];   // E_h [i][j]
    __shared__ bf16 QT[64 * NP];   // Qr tile [i'][u]; dG [i][i'] staging at tail
    __shared__ bf16 ET[64 * NP];   // Er tile [i][u]
    const int b = blockIdx.x, c = blockIdx.y, qt = blockIdx.z;
    const int tid = threadIdx.x;
    const int w = tid >> 6, l = tid & 63, q = l >> 4, l16 = l & 15;
    const int row = tid >> 2, col = (tid & 3) * 16;

    // R A-frags straight from global fp32 (rows u = c*64 + w*16 + l16)
    const float* rrow = rp + ((size_t)b * N_T + c * 64 + w * 16 + l16) * NN;
    const bf16x8 a0 = ldcvt8(rrow + q * 8);
    const bf16x8 a1 = ldcvt8(rrow + 32 + q * 8);

    if (qt == 0) {
        const float* src = rp + ((size_t)b * N_T + c * 64 + row) * NN + col;
        bf16* d = Rbf + ((size_t)b * N_T + c * 64 + row) * NN + col;
        *(bf16x8*)d       = ldcvt8(src);
        *(bf16x8*)(d + 8) = ldcvt8(src + 8);
    }

    f32x4 dacc[4];
#pragma unroll
    for (int ns = 0; ns < 4; ns++) { f32x4 z = {0.f, 0.f, 0.f, 0.f}; dacc[ns] = z; }

    for (int hh = 0; hh < 2; hh++) {
        const int h = qt * 2 + hh;
        {
            const float* qs = Qm + (size_t)h * 4096 + row * 64 + col;
            const float* es = Em + (size_t)h * 4096 + row * 64 + col;
            *(bf16x8*)&Ql[row * NP + col]     = ldcvt8(qs);
            *(bf16x8*)&Ql[row * NP + col + 8] = ldcvt8(qs + 8);
            *(bf16x8*)&El[row * NP + col]     = ldcvt8(es);
            *(bf16x8*)&El[row * NP + col + 8] = ldcvt8(es + 8);
        }
        __syncthreads();
        const size_t tb = (((size_t)(b * N_C + c)) * N_H + h) * 4096;
#pragma unroll
        for (int ns = 0; ns < 4; ns++) {
            bf16x8 b0 = *(const bf16x8*)&Ql[(ns * 16 + l16) * NP + q * 8];
            bf16x8 b1 = *(const bf16x8*)&Ql[(ns * 16 + l16) * NP + 32 + q * 8];
            f32x4 z = {0.f, 0.f, 0.f, 0.f};
            f32x4 s = mfma16(a0, b0, z);
            s = mfma16(a1, b1, s);
            bf16x4 p;
#pragma unroll
            for (int r = 0; r < 4; r++) p[r] = (bf16)s[r];
#pragma unroll
            for (int r = 0; r < 4; r++)
                Qrd[tb + (w * 16 + q * 4 + r) * 64 + ns * 16 + l16] = p[r];
            *(bf16x4*)&QT[(ns * 16 + l16) * NP + w * 16 + q * 4] = p;  // [i'][u]
            b0 = *(const bf16x8*)&El[(ns * 16 + l16) * NP + q * 8];
            b1 = *(const bf16x8*)&El[(ns * 16 + l16) * NP + 32 + q * 8];
            f32x4 s2 = mfma16(a0, b0, z);
            s2 = mfma16(a1, b1, s2);
#pragma unroll
            for (int r = 0; r < 4; r++) p[r] = (bf16)s2[r];
            *(bf16x4*)&ET[(ns * 16 + l16) * NP + w * 16 + q * 4] = p;  // [i][u]
        }
        __syncthreads();
        {
            const bf16x8 qa0 = *(const bf16x8*)&QT[(w * 16 + l16) * NP + q * 8];
            const bf16x8 qa1 = *(const bf16x8*)&QT[(w * 16 + l16) * NP + 32 + q * 8];
#pragma unroll
            for (int ns = 0; ns < 4; ns++) {
                const bf16x8 e0 = *(const bf16x8*)&ET[(ns * 16 + l16) * NP + q * 8];
                const bf16x8 e1 = *(const bf16x8*)&ET[(ns * 16 + l16) * NP + 32 + q * 8];
                dacc[ns] = mfma16(qa0, e0, dacc[ns]);
                dacc[ns] = mfma16(qa1, e1, dacc[ns]);
            }
        }
        {
            const bf16x8 v0 = *(const bf16x8*)&ET[row * NP + col];
            const bf16x8 v1 = *(const bf16x8*)&ET[row * NP + col + 8];
            bf16* d = Erd + tb + row * 64 + col;
            *(bf16x8*)d = v0;
            *(bf16x8*)(d + 8) = v1;
        }
        __syncthreads();
    }
#pragma unroll
    for (int ns = 0; ns < 4; ns++) {
        bf16x4 p;
#pragma unroll
        for (int r = 0; r < 4; r++) p[r] = (bf16)dacc[ns][r];
        *(bf16x4*)&QT[(ns * 16 + l16) * NP + w * 16 + q * 4] = p;
    }
    __syncthreads();
    {
        bf16* dst = dGq + (((size_t)(b * N_C + c)) * 4 + qt) * 4096 + row * 64 + col;
        *(bf16x8*)dst       = *(const bf16x8*)&QT[row * NP + col];
        *(bf16x8*)(dst + 8) = *(const bf16x8*)&QT[row * NP + col + 8];
    }
}

// ---------------------------------------------------------------------------
// K2: fold the 4 head-quarters: dG8[b,c] = sum_qt dGq[b,c,qt].
// 4 independent 16 B loads/thread; grid (D_B, N_C): linear%8 = b.
// ---------------------------------------------------------------------------
__global__ __launch_bounds__(256, 4) void k_fold(const bf16* __restrict__ dGq,
                                                 bf16* __restrict__ dG8)
{
    const int b = blockIdx.x, c = blockIdx.y;
    const size_t base = ((size_t)(b * N_C + c)) * 4 * 4096 + threadIdx.x * 16;
    float s[16];
#pragma unroll
    for (int k = 0; k < 16; k++) s[k] = 0.f;
#pragma unroll
    for (int qt = 0; qt < 4; qt++) {
        const bf16x8 v0 = *(const bf16x8*)(dGq + base + (size_t)qt * 4096);
        const bf16x8 v1 = *(const bf16x8*)(dGq + base + (size_t)qt * 4096 + 8);
#pragma unroll
        for (int k = 0; k < 8; k++) { s[k] += (float)v0[k]; s[8 + k] += (float)v1[k]; }
    }
    bf16x8 o0, o1;
#pragma unroll
    for (int k = 0; k < 8; k++) { o0[k] = (bf16)s[k]; o1[k] = (bf16)s[8 + k]; }
    bf16* dst = dG8 + (size_t)(b * N_C + c) * 4096 + threadIdx.x * 16;
    *(bf16x8*)dst = o0;
    *(bf16x8*)(dst + 8) = o1;
}

// ---------------------------------------------------------------------------
// One head of the K3 loop, fully static (NU = 2 or 4). Writes S to the given
// slab, reads it back (same-wave in-order DS), accumulates S*Er.
// ---------------------------------------------------------------------------
template <int NU>
static __device__ __forceinline__ void head_iter(
    const bf16* __restrict__ Qh, const bf16* __restrict__ Eh,
    bf16* __restrict__ Sw, const bf16x8 ra0, const bf16x8 ra1,
    int l16, int q, int tbase, f32x4 (&acc)[4])
{
#pragma unroll
    for (int nu = 0; nu < NU; nu++) {
        const bf16x8 b0 = *(const bf16x8*)&Qh[(nu * 16 + l16) * 64 + q * 8];
        const bf16x8 b1 = *(const bf16x8*)&Qh[(nu * 16 + l16) * 64 + 32 + q * 8];
        f32x4 z = {0.f, 0.f, 0.f, 0.f};
        f32x4 sv = mfma16(ra0, b0, z);
        sv = mfma16(ra1, b1, sv);
        const int u_loc = nu * 16 + l16;
#pragma unroll
        for (int r = 0; r < 4; r++) {
            const int t_loc = tbase + q * 4 + r;
            Sw[(q * 4 + r) * NP + u_loc] = (u_loc <= t_loc) ? (bf16)sv[r] : (bf16)0.f;
        }
    }
    const bf16x8 sa0 = *(const bf16x8*)&Sw[l16 * NP + q * 8];
#pragma unroll
    for (int ns = 0; ns < 4; ns++) {
        const bf16x8 e0 = *(const bf16x8*)&Eh[(ns * 16 + l16) * 64 + q * 8];
        acc[ns] = mfma16(sa0, e0, acc[ns]);
    }
    if (NU == 4) {
        const bf16x8 sa1 = *(const bf16x8*)&Sw[l16 * NP + 32 + q * 8];
#pragma unroll
        for (int ns = 0; ns < 4; ns++) {
            const bf16x8 e1 = *(const bf16x8*)&Eh[(ns * 16 + l16) * 64 + 32 + q * 8];
            acc[ns] = mfma16(sa1, e1, acc[ns]);
        }
    }
}

// ---------------------------------------------------------------------------
// K3: block (b, c, half) computes out rows [c*64 + half*32, +32).
// Register scan of <=31 folded tiles (batch-4); head loop fully unrolled with
// constexpr NU and PING-PONG per-wave S slabs (no WAR between heads -> loads
// of head h+1 hoist above head h's LDS round-trip). Gb publish + one barrier
// deferred to the end. Grid (D_B, N_C, 2): linear%8 = b.
// ---------------------------------------------------------------------------
__global__ __launch_bounds__(256, 4) void k_out(
    const bf16* __restrict__ dG8, const bf16* __restrict__ Rbf,
    const bf16* __restrict__ Qrd, const bf16* __restrict__ Erd,
    float* __restrict__ out)
{
    __shared__ bf16 Gb[64 * NP];          // Gcum [i][i'] (written AFTER head loop)
    __shared__ bf16 Sl[4 * 2 * 16 * NP];  // per-wave ping-pong S slabs
    __shared__ float Ob[32 * 65];         // h-group reduction
    const int b = blockIdx.x, c = blockIdx.y, half = blockIdx.z;
    const int tid = threadIdx.x;
    const int w = tid >> 6, l = tid & 63, q = l >> 4, l16 = l & 15;
    const int s = w & 1, g = w >> 1;

    // A-frags: R rows t = c*64 + half*32 + s*16 + l16
    const int trow = c * 64 + half * 32 + s * 16 + l16;
    const bf16x8 ra0 = *(const bf16x8*)&Rbf[((size_t)b * N_T + trow) * NN + q * 8];
    const bf16x8 ra1 = *(const bf16x8*)&Rbf[((size_t)b * N_T + trow) * NN + 32 + q * 8];

    // ---- scan (registers only; no LDS, no barrier yet), batch-4 prefetch
    float run[16];
#pragma unroll
    for (int k = 0; k < 16; k++) run[k] = 0.f;
    {
        const bf16* base = dG8 + (size_t)b * N_C * 4096 + tid * 16;
        int t = 0;
        for (; t + 4 <= c; t += 4) {
            bf16x8 v[4][2];
#pragma unroll
            for (int j = 0; j < 4; j++) {
                v[j][0] = *(const bf16x8*)(base + (size_t)(t + j) * 4096);
                v[j][1] = *(const bf16x8*)(base + (size_t)(t + j) * 4096 + 8);
            }
#pragma unroll
            for (int j = 0; j < 4; j++)
#pragma unroll
                for (int k = 0; k < 8; k++) {
                    run[k] += (float)v[j][0][k];
                    run[8 + k] += (float)v[j][1][k];
                }
        }
        for (; t < c; t++) {
            const bf16x8 v0 = *(const bf16x8*)(base + (size_t)t * 4096);
            const bf16x8 v1 = *(const bf16x8*)(base + (size_t)t * 4096 + 8);
#pragma unroll
            for (int k = 0; k < 8; k++) { run[k] += (float)v0[k]; run[8 + k] += (float)v1[k]; }
        }
    }

    // ---- head loop (barrier-free; ping-pong per-wave S slabs; static NU)
    bf16* Sw0 = Sl + (w * 2 + 0) * 16 * NP;
    bf16* Sw1 = Sl + (w * 2 + 1) * 16 * NP;
    const int tbase = half * 32 + s * 16;
    const size_t hb = (((size_t)(b * N_C + c)) * N_H + g * 4) * 4096;
    const bf16* Qg = Qrd + hb;   // 4 heads, 4096 apart
    const bf16* Eg = Erd + hb;
    f32x4 acc[4];
#pragma unroll
    for (int ns = 0; ns < 4; ns++) { f32x4 z = {0.f, 0.f, 0.f, 0.f}; acc[ns] = z; }

    if (half) {
#pragma unroll
        for (int hh = 0; hh < 4; hh++)
            head_iter<4>(Qg + (size_t)hh * 4096, Eg + (size_t)hh * 4096,
                         (hh & 1) ? Sw1 : Sw0, ra0, ra1, l16, q, tbase, acc);
    } else {
#pragma unroll
        for (int hh = 0; hh < 4; hh++)
            head_iter<2>(Qg + (size_t)hh * 4096, Eg + (size_t)hh * 4096,
                         (hh & 1) ? Sw1 : Sw0, ra0, ra1, l16, q, tbase, acc);
    }

    // ---- publish Gb (from scan regs) + Ob (g==0 partials); ONE barrier
    {
        // elem idx = tid*16+k -> i = tid>>2, i' = (tid&3)*16 + k
        bf16x8 o0, o1;
#pragma unroll
        for (int k = 0; k < 8; k++) { o0[k] = (bf16)run[k]; o1[k] = (bf16)run[8 + k]; }
        *(bf16x8*)&Gb[(tid >> 2) * NP + (tid & 3) * 16] = o0;
        *(bf16x8*)&Gb[(tid >> 2) * NP + (tid & 3) * 16 + 8] = o1;
    }
    if (g == 0) {
#pragma unroll
        for (int ns = 0; ns < 4; ns++)
#pragma unroll
            for (int r = 0; r < 4; r++)
                Ob[(s * 16 + q * 4 + r) * 65 + ns * 16 + l16] = acc[ns][r];
    }
    __syncthreads();
    if (g == 1) {
        // prefix term: O += R_t * Gcum, B storage [n=i][k=i'] = Gb
#pragma unroll
        for (int ns = 0; ns < 4; ns++) {
            const bf16x8 g0 = *(const bf16x8*)&Gb[(ns * 16 + l16) * NP + q * 8];
            const bf16x8 g1 = *(const bf16x8*)&Gb[(ns * 16 + l16) * NP + 32 + q * 8];
            acc[ns] = mfma16(ra0, g0, acc[ns]);
            acc[ns] = mfma16(ra1, g1, acc[ns]);
        }
        const int t0 = c * 64 + half * 32;
#pragma unroll
        for (int ns = 0; ns < 4; ns++)
#pragma unroll
            for (int r = 0; r < 4; r++) {
                const float sum = acc[ns][r] + Ob[(s * 16 + q * 4 + r) * 65 + ns * 16 + l16];
                out[((size_t)b * N_T + t0 + s * 16 + q * 4 + r) * NN + ns * 16 + l16] = sum;
            }
    }
}

// ---------------------------------------------------------------------------
extern "C" void kernel_launch(void* const* d_in, const int* in_sizes, int n_in,
                              void* d_out, int out_size, void* d_ws, size_t ws_size,
                              hipStream_t stream) {
    const float* rp = (const float*)d_in[0];   // (8, 2048, 64) fp32
    const float* Qm = (const float*)d_in[1];   // (8, 64, 64)
    const float* Em = (const float*)d_in[2];   // (8, 64, 64)
    float* out = (float*)d_out;                // (8, 2048, 64) fp32

    // ws: dGq 8.4 MB + Rbf 2 MB + Qrd 16.8 MB + Erd 16.8 MB + dG8 2.1 MB
    bf16* dGq = (bf16*)d_ws;
    bf16* Rbf = dGq + (size_t)D_B * N_C * 4 * 4096;
    bf16* Qrd = Rbf + (size_t)D_B * N_T * NN;
    bf16* Erd = Qrd + (size_t)D_B * N_C * N_H * 4096;
    bf16* dG8 = Erd + (size_t)D_B * N_C * N_H * 4096;

    k_dg<<<dim3(D_B, N_C, 4), 256, 0, stream>>>(rp, Qm, Em, dGq, Rbf, Qrd, Erd);
    k_fold<<<dim3(D_B, N_C), 256, 0, stream>>>(dGq, dG8);
    k_out<<<dim3(D_B, N_C, 2), 256, 0, stream>>>(dG8, Rbf, Qrd, Erd, out);
}